// Round 3
// baseline (573.256 us; speedup 1.0000x reference)
//
#include <hip/hip_runtime.h>
#include <hip/hip_fp16.h>
#include <math.h>

// ---------------------------------------------------------------------------
// GCN 3-layer forward, round 13.
// out[i] = dinv[i] * ( sum_{e:dst=i} Hs[src] + Hs[i] ) + b,  Hs = (X@W)*dinv.
// Round-13 delta (fixing round-12's latency regression; residency confirmed):
//  - agg16: one wave per (node, chunk). 64 lanes = 32 edge slots x 2
//    feature-half lanes (16B gathers from the L2-resident 3.2MB chunk slice).
//    deg~32 -> edge loop is ONE uniform iteration (was: 4 nodes/wave,
//    max-deg divergence, 2-deep MLP -> VALUBusy 29%).
//  - chunk-major dispatch preserved (blockIdx/nwgpc), layout [4][n][16] fp16.
//  - linear kernels write/read chunked layout (unchanged from round 12).
// ---------------------------------------------------------------------------

#define WS_ALIGN(x) (((x) + 255) & ~(size_t)255)
#define BKN 128                 // nodes per bin/sort bucket
#define CAP 4608                // slab capacity per bucket (mean 4092; +8 sigma)
#define EPT 8                   // edges per thread in bin kernel
#define BIN_THR 512
#define BIN_CHUNK (BIN_THR * EPT)  // 4096 edges per WG

typedef _Float16 half8 __attribute__((ext_vector_type(8)));
typedef float floatx4 __attribute__((ext_vector_type(4)));
typedef int intx4 __attribute__((ext_vector_type(4)));

// ---------------- binning: LDS-histogram chunked scatter ----------------
__global__ __launch_bounds__(BIN_THR) void bin_kernel(
    const int* __restrict__ src, const int* __restrict__ dst,
    int* __restrict__ cur, int* __restrict__ slab, int E, int NB) {
    __shared__ int counts[784];  // NB = 782
    const int tid = threadIdx.x;
    const int base = blockIdx.x * BIN_CHUNK + tid * EPT;  // contiguous per thread
    for (int i = tid; i < NB; i += BIN_THR) counts[i] = 0;
    __syncthreads();
    int b[EPT], w[EPT], lpos[EPT];
    #pragma unroll
    for (int k = 0; k < EPT; ++k) {
        int e = base + k;
        if (e < E) {
            int s = src[e], d = dst[e];   // vectorized int4 loads
            b[k] = d >> 7;
            w[k] = (s << 7) | (d & 127);
        } else b[k] = -1;
    }
    #pragma unroll
    for (int k = 0; k < EPT; ++k)
        if (b[k] >= 0) lpos[k] = atomicAdd(&counts[b[k]], 1);
    __syncthreads();
    for (int i = tid; i < NB; i += BIN_THR) {
        int c = counts[i];
        counts[i] = c ? atomicAdd(&cur[i], c) : 0;  // reserve contiguous run
    }
    __syncthreads();
    #pragma unroll
    for (int k = 0; k < EPT; ++k) {
        if (b[k] >= 0) {
            int pos = counts[b[k]] + lpos[k];
            if (pos < CAP) slab[(size_t)b[k] * CAP + pos] = w[k];
        }
    }
}

// ---------------- per-bucket counting sort -> per-node CSR + dinv ----------------
__global__ __launch_bounds__(512) void bucket_sort_kernel(
    const int* __restrict__ slab, const int* __restrict__ cur,
    int* __restrict__ srcS, int2* __restrict__ rows,
    float* __restrict__ dinv, int n) {
    __shared__ int cnt[BKN], s[BKN], cursor[BKN];
    const int b = blockIdx.x, tid = threadIdx.x;
    const int m = min(cur[b], CAP);
    const int* sp = slab + (size_t)b * CAP;
    if (tid < BKN) cnt[tid] = 0;
    __syncthreads();
    for (int j = tid; j < m; j += 512) atomicAdd(&cnt[sp[j] & (BKN - 1)], 1);
    __syncthreads();
    if (tid < BKN) s[tid] = cnt[tid];
    __syncthreads();
    // Hillis-Steele inclusive scan over BKN entries
    for (int off = 1; off < BKN; off <<= 1) {
        int v = 0;
        if (tid < BKN && tid >= off) v = s[tid - off];
        __syncthreads();
        if (tid < BKN) s[tid] += v;
        __syncthreads();
    }
    if (tid < BKN) {
        int ofs = s[tid] - cnt[tid];  // exclusive
        cursor[tid] = ofs;
        int node = b * BKN + tid;
        if (node < n) {
            rows[node] = make_int2(b * CAP + ofs, b * CAP + ofs + cnt[tid]);
            dinv[node] = rsqrtf((float)(cnt[tid] + 1));  // +1 self loop
        }
    }
    __syncthreads();
    for (int j = tid; j < m; j += 512) {
        int w = sp[j];
        int p = atomicAdd(&cursor[w & (BKN - 1)], 1);
        srcS[(size_t)b * CAP + p] = w >> 7;  // writes land in an 18KB window
    }
}

// ---------------- MFMA linear (fp32 input): chunked Y[4][n][16] ----------------
// 4 node-tiles per WG: W staged once per 256 nodes.
// mfma_f32_16x16x32_f16: A[m=lane&15][k=(lane>>4)*8+j], C/D col=lane&15, row=quad*4+r.
template <int K>
__global__ __launch_bounds__(256) void linear_mfma_f32_kernel(
    const float* __restrict__ Xf, const float* __restrict__ W,
    const float* __restrict__ dinv, _Float16* __restrict__ Y, int n) {
    constexpr int KC = K / 32;
    __shared__ _Float16 Bf[KC * 4 * 64 * 8];  // B-fragment order; K=128 -> 16KB
    const int tid = threadIdx.x;
    for (int i = tid; i < KC * 4 * 64 * 8; i += 256) {
        int j = i & 7, lane = (i >> 3) & 63, tile = (i >> 9) & 3, kc = i >> 11;
        int k = kc * 32 + ((lane >> 4) << 3) + j;
        int col = tile * 16 + (lane & 15);
        Bf[i] = (_Float16)W[k * 64 + col];
    }
    __syncthreads();
    const int lane = tid & 63, wid = tid >> 6;
    const int mrow = lane & 15, quad = lane >> 4;
    #pragma unroll
    for (int tt = 0; tt < 4; ++tt) {
        const int base = (blockIdx.x * 4 + tt) * 64 + wid * 16;
        if (base >= n) continue;
        const int anode = min(base + mrow, n - 1);
        floatx4 acc[4] = {{0, 0, 0, 0}, {0, 0, 0, 0}, {0, 0, 0, 0}, {0, 0, 0, 0}};
        #pragma unroll
        for (int kc = 0; kc < KC; ++kc) {
            float4 xa = *(const float4*)&Xf[(size_t)anode * K + kc * 32 + quad * 8];
            float4 xb = *(const float4*)&Xf[(size_t)anode * K + kc * 32 + quad * 8 + 4];
            half8 a;
            a[0] = (_Float16)xa.x; a[1] = (_Float16)xa.y; a[2] = (_Float16)xa.z; a[3] = (_Float16)xa.w;
            a[4] = (_Float16)xb.x; a[5] = (_Float16)xb.y; a[6] = (_Float16)xb.z; a[7] = (_Float16)xb.w;
            #pragma unroll
            for (int t = 0; t < 4; ++t) {
                half8 b = *(const half8*)&Bf[((kc * 4 + t) * 64 + lane) * 8];
                acc[t] = __builtin_amdgcn_mfma_f32_16x16x32_f16(a, b, acc[t], 0, 0, 0);
            }
        }
        #pragma unroll
        for (int r = 0; r < 4; ++r) {
            int node = base + quad * 4 + r;
            if (node < n) {
                float di = dinv[node];
                #pragma unroll
                for (int t = 0; t < 4; ++t)   // t == feature chunk
                    Y[((size_t)t * n + node) * 16 + mrow] = (_Float16)(acc[t][r] * di);
            }
        }
    }
}

// ---------------- MFMA linear (fp16 chunked input), K=64, 4 tiles per WG ----------------
__global__ __launch_bounds__(256) void linear_mfma_f16_kernel(
    const _Float16* __restrict__ Xh, const float* __restrict__ W,
    const float* __restrict__ dinv, _Float16* __restrict__ Y, int n) {
    constexpr int KC = 2;
    __shared__ _Float16 Bf[KC * 4 * 64 * 8];  // 8KB
    const int tid = threadIdx.x;
    for (int i = tid; i < KC * 4 * 64 * 8; i += 256) {
        int j = i & 7, lane = (i >> 3) & 63, tile = (i >> 9) & 3, kc = i >> 11;
        int k = kc * 32 + ((lane >> 4) << 3) + j;
        int col = tile * 16 + (lane & 15);
        Bf[i] = (_Float16)W[k * 64 + col];
    }
    __syncthreads();
    const int lane = tid & 63, wid = tid >> 6;
    const int mrow = lane & 15, quad = lane >> 4;
    #pragma unroll
    for (int tt = 0; tt < 4; ++tt) {
        const int base = (blockIdx.x * 4 + tt) * 64 + wid * 16;
        if (base >= n) continue;
        const int anode = min(base + mrow, n - 1);
        floatx4 acc[4] = {{0, 0, 0, 0}, {0, 0, 0, 0}, {0, 0, 0, 0}, {0, 0, 0, 0}};
        #pragma unroll
        for (int kc = 0; kc < KC; ++kc) {
            // chunked read: feature f = kc*32 + quad*8 + j  ->  chunk 2*kc + (quad>>1)
            half8 a = *(const half8*)&Xh[((size_t)(2 * kc + (quad >> 1)) * n + anode) * 16 + (quad & 1) * 8];
            #pragma unroll
            for (int t = 0; t < 4; ++t) {
                half8 b = *(const half8*)&Bf[((kc * 4 + t) * 64 + lane) * 8];
                acc[t] = __builtin_amdgcn_mfma_f32_16x16x32_f16(a, b, acc[t], 0, 0, 0);
            }
        }
        #pragma unroll
        for (int r = 0; r < 4; ++r) {
            int node = base + quad * 4 + r;
            if (node < n) {
                float di = dinv[node];
                #pragma unroll
                for (int t = 0; t < 4; ++t)   // t == feature chunk
                    Y[((size_t)t * n + node) * 16 + mrow] = (_Float16)(acc[t][r] * di);
            }
        }
    }
}

// ---------------- linear3: Y16[n][8] = fp16(pad8((Xh@W3)*dinv)), chunked X ----------------
__global__ __launch_bounds__(256) void linear3_kernel(const _Float16* __restrict__ Xh,
                                                      const float* __restrict__ W,
                                                      const float* __restrict__ dinv,
                                                      __half* __restrict__ Y, int n) {
    __shared__ float Wl[64 * 6];
    __shared__ float Xs[32][65];
    const int tid = threadIdx.x;
    for (int i = tid; i < 64 * 6; i += 256) Wl[i] = W[i];
    const int sub = tid >> 3;
    const int feat = tid & 7;
    const int sr = tid >> 3, c8 = tid & 7;        // staging: node offset, half8 group
    for (int base = blockIdx.x * 32; base < n; base += gridDim.x * 32) {
        __syncthreads();
        {   // stage 32 nodes x 64 feats from chunked layout, one half8 per thread
            int node = base + sr;
            half8 v;
            if (node < n)
                v = *(const half8*)&Xh[((size_t)(c8 >> 1) * n + node) * 16 + (c8 & 1) * 8];
            else
                #pragma unroll
                for (int k = 0; k < 8; ++k) v[k] = (_Float16)0.f;
            #pragma unroll
            for (int k = 0; k < 8; ++k) Xs[sr][c8 * 8 + k] = (float)v[k];
        }
        __syncthreads();
        int node = base + sub;
        if (node < n) {
            float r = 0.f;
            if (feat < 6) {
                float acc = 0.f;
                #pragma unroll
                for (int k = 0; k < 64; ++k) acc = fmaf(Xs[sub][k], Wl[k * 6 + feat], acc);
                r = acc * dinv[node];
            }
            Y[(size_t)node * 8 + feat] = __float2half_rn(r);
        }
    }
}

// ---------------- chunked aggregate: wave per (node, chunk) ----------------
// Hc layout [4][n][16] fp16; chunk slice = 3.2MB -> L2-resident per XCD.
// Dispatch chunk-major (blockIdx / nwgpc) so concurrent WGs share one chunk.
// 64 lanes = 32 edge slots x 2 feature-half lanes; deg~32 -> 1 uniform iter.
__global__ __launch_bounds__(256) void agg16_kernel(
    const _Float16* __restrict__ Hc, const float* __restrict__ dinv,
    const int* __restrict__ srcS, const int2* __restrict__ rows,
    const float* __restrict__ bias, _Float16* __restrict__ Out,
    int n, int nwgpc, int do_relu) {
    const int chunk = blockIdx.x / nwgpc;
    const int node = (blockIdx.x % nwgpc) * 4 + (threadIdx.x >> 6);
    if (node >= n) return;
    const int lane = threadIdx.x & 63;
    const int slot = lane >> 1;         // edge slot 0..31
    const int h = lane & 1;             // feature half [h*8, h*8+8)
    const char* Hb = (const char*)(Hc + (size_t)chunk * n * 16);
    const int2 row = rows[node];
    const int end = row.y;
    half8 hA, hB;
    #pragma unroll
    for (int i = 0; i < 8; ++i) { hA[i] = (_Float16)0.f; hB[i] = (_Float16)0.f; }
    int jj = row.x + slot;
    for (; jj + 32 < end; jj += 64) {   // 64 edges: 2 gathers in flight
        int s0 = __builtin_nontemporal_load(srcS + jj);
        int s1 = __builtin_nontemporal_load(srcS + jj + 32);
        half8 v0 = *(const half8*)(Hb + (s0 << 5) + (h << 4));
        half8 v1 = *(const half8*)(Hb + (s1 << 5) + (h << 4));
        hA += v0; hB += v1;
    }
    if (jj < end) {                     // typical case: the only iteration
        int s0 = __builtin_nontemporal_load(srcS + jj);
        hA += *(const half8*)(Hb + (s0 << 5) + (h << 4));
    }
    half8 ht = hA + hB;
    #pragma unroll
    for (int mask = 2; mask <= 32; mask <<= 1) {  // fold over 32 slots (bits 1..5)
        int4 ci = *(int4*)&ht, oi;
        oi.x = __shfl_xor(ci.x, mask);
        oi.y = __shfl_xor(ci.y, mask);
        oi.z = __shfl_xor(ci.z, mask);
        oi.w = __shfl_xor(ci.w, mask);
        ht += *(half8*)&oi;
    }
    half8 self = *(const half8*)(Hb + (node << 5) + (h << 4));
    const float di = dinv[node];
    const float* bp = bias + chunk * 16 + h * 8;
    half8 o;
    #pragma unroll
    for (int i = 0; i < 8; ++i) {
        float t = ((float)ht[i] + (float)self[i]) * di + bp[i];
        if (do_relu) t = fmaxf(t, 0.f);
        o[i] = (_Float16)t;
    }
    if (lane < 2) {  // 2 lanes per node, 32B contiguous
        intx4* op = (intx4*)((char*)Out + (size_t)chunk * n * 32 + (node << 5) + (h << 4));
        __builtin_nontemporal_store(*(intx4*)&o, op);
    }
}

// ---------------- aggregate 6 feats + bias + log_softmax: lane-per-edge ----------------
__global__ __launch_bounds__(256) void agg6_lsm_kernel(
    const _Float16* __restrict__ Hs6, const float* __restrict__ dinv,
    const int* __restrict__ srcS, const int2* __restrict__ rows,
    const float* __restrict__ bias, float* __restrict__ out, int n) {
    const int wave = (blockIdx.x * blockDim.x + threadIdx.x) >> 6;
    const int lane = threadIdx.x & 63;
    if (wave >= n) return;
    const int2 row = rows[wave];
    const int beg = row.x, end = row.y;
    half8 ht;
    #pragma unroll
    for (int i = 0; i < 8; ++i) ht[i] = (_Float16)0.f;
    for (int j = beg + lane; j < end; j += 64) {          // 1 iter typ. (deg~32)
        int s = __builtin_nontemporal_load(srcS + j);
        ht += *(const half8*)&Hs6[(size_t)s * 8];          // 16B row gather
    }
    #pragma unroll
    for (int mask = 1; mask <= 32; mask <<= 1) {          // packed fold, 64 lanes
        int4 ci = *(int4*)&ht, oi;
        oi.x = __shfl_xor(ci.x, mask);
        oi.y = __shfl_xor(ci.y, mask);
        oi.z = __shfl_xor(ci.z, mask);
        oi.w = __shfl_xor(ci.w, mask);
        ht += *(half8*)&oi;
    }
    // all lanes now hold the full edge-sum; redundant per-lane epilogue
    half8 self = *(const half8*)&Hs6[(size_t)wave * 8];
    const float di = dinv[wave];
    float a[6];
    #pragma unroll
    for (int q = 0; q < 6; ++q)
        a[q] = ((float)ht[q] + (float)self[q]) * di + bias[q];
    float mx = a[0];
    #pragma unroll
    for (int q = 1; q < 6; ++q) mx = fmaxf(mx, a[q]);
    float sum = 0.f;
    #pragma unroll
    for (int q = 0; q < 6; ++q) sum += expf(a[q] - mx);
    float lse = mx + logf(sum);
    if (lane == 0) {
        float* op = &out[(size_t)wave * 6];               // 24B-aligned -> 8B stores
        *(float2*)(op)     = make_float2(a[0] - lse, a[1] - lse);
        *(float2*)(op + 2) = make_float2(a[2] - lse, a[3] - lse);
        *(float2*)(op + 4) = make_float2(a[4] - lse, a[5] - lse);
    }
}

// ---------------------------------------------------------------------------
extern "C" void kernel_launch(void* const* d_in, const int* in_sizes, int n_in,
                              void* d_out, int out_size, void* d_ws, size_t ws_size,
                              hipStream_t stream) {
    const float* x  = (const float*)d_in[0];
    const int*   ei = (const int*)d_in[1];
    const float* W1 = (const float*)d_in[2];
    const float* b1 = (const float*)d_in[3];
    const float* W2 = (const float*)d_in[4];
    const float* b2 = (const float*)d_in[5];
    const float* W3 = (const float*)d_in[6];
    const float* b3 = (const float*)d_in[7];
    float* out = (float*)d_out;

    const int n = in_sizes[0] / 128;  // 100000
    const int E = in_sizes[1] / 2;    // 3200000
    const int* src = ei;
    const int* dst = ei + E;
    const int NB = (n + BKN - 1) / BKN;  // 782

    // ---- workspace carve ----
    char* ws = (char*)d_ws;
    auto carve = [&](size_t bytes) { char* p = ws; ws += WS_ALIGN(bytes); return p; };
    int*      cur  = (int*)     carve((size_t)NB * 4);
    float*    dinv = (float*)   carve((size_t)n * 4);
    int*      slab = (int*)     carve((size_t)NB * CAP * 4);   // 14.4 MB
    int*      srcS = (int*)     carve((size_t)NB * CAP * 4);   // 14.4 MB
    int2*     rows = (int2*)    carve((size_t)n * 8);
    _Float16* hsA  = (_Float16*)carve((size_t)n * 64 * 2 + 4096);   // 12.8 MB, chunked [4][n][16]
    _Float16* hsB  = (_Float16*)carve((size_t)n * 64 * 2 + 4096);   // 12.8 MB, chunked [4][n][16]
    _Float16* hsC  = (_Float16*)carve((size_t)n * 8 * 2);           // 1.6 MB
    (void)ws_size; (void)n_in; (void)out_size;

    // ---- build CSR ----
    (void)hipMemsetAsync(cur, 0, (size_t)NB * 4, stream);
    bin_kernel<<<(E + BIN_CHUNK - 1) / BIN_CHUNK, BIN_THR, 0, stream>>>(src, dst, cur, slab, E, NB);
    bucket_sort_kernel<<<NB, 512, 0, stream>>>(slab, cur, srcS, rows, dinv, n);

    const int nwgpc = (n + 3) / 4;         // WGs per chunk (1 node/wave, 4 waves/WG)
    const int linGrid = (n + 255) / 256;   // 256 nodes per WG (4 tiles)

    // ---- layer 1 ----
    linear_mfma_f32_kernel<128><<<linGrid, 256, 0, stream>>>(x, W1, dinv, hsA, n);
    agg16_kernel<<<nwgpc * 4, 256, 0, stream>>>(hsA, dinv, srcS, rows, b1, hsB, n, nwgpc, 1);

    // ---- layer 2 ----
    linear_mfma_f16_kernel<<<linGrid, 256, 0, stream>>>(hsB, W2, dinv, hsA, n);
    agg16_kernel<<<nwgpc * 4, 256, 0, stream>>>(hsA, dinv, srcS, rows, b2, hsB, n, nwgpc, 1);

    // ---- layer 3 ----
    linear3_kernel<<<2048, 256, 0, stream>>>(hsB, W3, dinv, (__half*)hsC, n);
    agg6_lsm_kernel<<<(n + 3) / 4, 256, 0, stream>>>(hsC, dinv, srcS, rows, b3, out, n);
}

// Round 4
// 370.334 us; speedup vs baseline: 1.5479x; 1.5479x over previous
//
#include <hip/hip_runtime.h>
#include <hip/hip_fp16.h>
#include <math.h>

// ---------------------------------------------------------------------------
// GCN 3-layer forward, round 14 (revert to round-11 structure + NT hints).
// out[i] = dinv[i] * ( sum_{e:dst=i} Hs[src] + Hs[i] ) + b,  Hs = (X@W)*dinv.
// Round-14 delta vs round-11:
//  - agg64: srcS loads + Out stores NON-TEMPORAL (evict-first) so the 2x
//    12.8MB streams stop thrashing the 4MB/XCD L2 that caches the 12.8MB
//    gather target Hs -> higher gather hit rate (chunking rounds 12/13
//    proved residency helps but paid 2-4x VALU overhead; this pays none).
//  - agg64: self/dinv/bias loads hoisted above the edge loop (overlap
//    gather latency instead of serializing after the fold).
//  - agg6_lsm: NT srcS loads (protect the 1.6MB hsC gather table).
// ---------------------------------------------------------------------------

#define WS_ALIGN(x) (((x) + 255) & ~(size_t)255)
#define BKN 128                 // nodes per bin/sort bucket
#define CAP 4608                // slab capacity per bucket (mean 4092; +8 sigma)
#define EPT 8                   // edges per thread in bin kernel
#define BIN_THR 512
#define BIN_CHUNK (BIN_THR * EPT)  // 4096 edges per WG

typedef _Float16 half8 __attribute__((ext_vector_type(8)));
typedef float floatx4 __attribute__((ext_vector_type(4)));
typedef int intx4 __attribute__((ext_vector_type(4)));

// ---------------- binning: LDS-histogram chunked scatter ----------------
__global__ __launch_bounds__(BIN_THR) void bin_kernel(
    const int* __restrict__ src, const int* __restrict__ dst,
    int* __restrict__ cur, int* __restrict__ slab, int E, int NB) {
    __shared__ int counts[784];  // NB = 782
    const int tid = threadIdx.x;
    const int base = blockIdx.x * BIN_CHUNK + tid * EPT;  // contiguous per thread
    for (int i = tid; i < NB; i += BIN_THR) counts[i] = 0;
    __syncthreads();
    int b[EPT], w[EPT], lpos[EPT];
    #pragma unroll
    for (int k = 0; k < EPT; ++k) {
        int e = base + k;
        if (e < E) {
            int s = src[e], d = dst[e];   // vectorized int4 loads
            b[k] = d >> 7;
            w[k] = (s << 7) | (d & 127);
        } else b[k] = -1;
    }
    #pragma unroll
    for (int k = 0; k < EPT; ++k)
        if (b[k] >= 0) lpos[k] = atomicAdd(&counts[b[k]], 1);
    __syncthreads();
    for (int i = tid; i < NB; i += BIN_THR) {
        int c = counts[i];
        counts[i] = c ? atomicAdd(&cur[i], c) : 0;  // reserve contiguous run
    }
    __syncthreads();
    #pragma unroll
    for (int k = 0; k < EPT; ++k) {
        if (b[k] >= 0) {
            int pos = counts[b[k]] + lpos[k];
            if (pos < CAP) slab[(size_t)b[k] * CAP + pos] = w[k];
        }
    }
}

// ---------------- per-bucket counting sort -> per-node CSR + dinv ----------------
__global__ __launch_bounds__(512) void bucket_sort_kernel(
    const int* __restrict__ slab, const int* __restrict__ cur,
    int* __restrict__ srcS, int2* __restrict__ rows,
    float* __restrict__ dinv, int n) {
    __shared__ int cnt[BKN], s[BKN], cursor[BKN];
    const int b = blockIdx.x, tid = threadIdx.x;
    const int m = min(cur[b], CAP);
    const int* sp = slab + (size_t)b * CAP;
    if (tid < BKN) cnt[tid] = 0;
    __syncthreads();
    for (int j = tid; j < m; j += 512) atomicAdd(&cnt[sp[j] & (BKN - 1)], 1);
    __syncthreads();
    if (tid < BKN) s[tid] = cnt[tid];
    __syncthreads();
    // Hillis-Steele inclusive scan over BKN entries
    for (int off = 1; off < BKN; off <<= 1) {
        int v = 0;
        if (tid < BKN && tid >= off) v = s[tid - off];
        __syncthreads();
        if (tid < BKN) s[tid] += v;
        __syncthreads();
    }
    if (tid < BKN) {
        int ofs = s[tid] - cnt[tid];  // exclusive
        cursor[tid] = ofs;
        int node = b * BKN + tid;
        if (node < n) {
            rows[node] = make_int2(b * CAP + ofs, b * CAP + ofs + cnt[tid]);
            dinv[node] = rsqrtf((float)(cnt[tid] + 1));  // +1 self loop
        }
    }
    __syncthreads();
    for (int j = tid; j < m; j += 512) {
        int w = sp[j];
        int p = atomicAdd(&cursor[w & (BKN - 1)], 1);
        srcS[(size_t)b * CAP + p] = w >> 7;  // writes land in an 18KB window
    }
}

// ---------------- MFMA linear (fp32 input): Y16 = fp16((Xf@W)*dinv) ----------------
// 4 node-tiles per WG: W staged once per 256 nodes.
// mfma_f32_16x16x32_f16: A[m=lane&15][k=(lane>>4)*8+j], C/D col=lane&15, row=quad*4+r.
template <int K>
__global__ __launch_bounds__(256) void linear_mfma_f32_kernel(
    const float* __restrict__ Xf, const float* __restrict__ W,
    const float* __restrict__ dinv, _Float16* __restrict__ Y, int n) {
    constexpr int KC = K / 32;
    __shared__ _Float16 Bf[KC * 4 * 64 * 8];  // B-fragment order; K=128 -> 16KB
    const int tid = threadIdx.x;
    for (int i = tid; i < KC * 4 * 64 * 8; i += 256) {
        int j = i & 7, lane = (i >> 3) & 63, tile = (i >> 9) & 3, kc = i >> 11;
        int k = kc * 32 + ((lane >> 4) << 3) + j;
        int col = tile * 16 + (lane & 15);
        Bf[i] = (_Float16)W[k * 64 + col];
    }
    __syncthreads();
    const int lane = tid & 63, wid = tid >> 6;
    const int mrow = lane & 15, quad = lane >> 4;
    #pragma unroll
    for (int tt = 0; tt < 4; ++tt) {
        const int base = (blockIdx.x * 4 + tt) * 64 + wid * 16;
        if (base >= n) continue;
        const int anode = min(base + mrow, n - 1);
        floatx4 acc[4] = {{0, 0, 0, 0}, {0, 0, 0, 0}, {0, 0, 0, 0}, {0, 0, 0, 0}};
        #pragma unroll
        for (int kc = 0; kc < KC; ++kc) {
            float4 xa = *(const float4*)&Xf[(size_t)anode * K + kc * 32 + quad * 8];
            float4 xb = *(const float4*)&Xf[(size_t)anode * K + kc * 32 + quad * 8 + 4];
            half8 a;
            a[0] = (_Float16)xa.x; a[1] = (_Float16)xa.y; a[2] = (_Float16)xa.z; a[3] = (_Float16)xa.w;
            a[4] = (_Float16)xb.x; a[5] = (_Float16)xb.y; a[6] = (_Float16)xb.z; a[7] = (_Float16)xb.w;
            #pragma unroll
            for (int t = 0; t < 4; ++t) {
                half8 b = *(const half8*)&Bf[((kc * 4 + t) * 64 + lane) * 8];
                acc[t] = __builtin_amdgcn_mfma_f32_16x16x32_f16(a, b, acc[t], 0, 0, 0);
            }
        }
        #pragma unroll
        for (int r = 0; r < 4; ++r) {
            int node = base + quad * 4 + r;
            if (node < n) {
                float di = dinv[node];
                #pragma unroll
                for (int t = 0; t < 4; ++t)
                    Y[(size_t)node * 64 + t * 16 + mrow] = (_Float16)(acc[t][r] * di);
            }
        }
    }
}

// ---------------- MFMA linear (fp16 input), K=64, 4 tiles per WG ----------------
__global__ __launch_bounds__(256) void linear_mfma_f16_kernel(
    const _Float16* __restrict__ Xh, const float* __restrict__ W,
    const float* __restrict__ dinv, _Float16* __restrict__ Y, int n) {
    constexpr int K = 64, KC = 2;
    __shared__ _Float16 Bf[KC * 4 * 64 * 8];  // 8KB
    const int tid = threadIdx.x;
    for (int i = tid; i < KC * 4 * 64 * 8; i += 256) {
        int j = i & 7, lane = (i >> 3) & 63, tile = (i >> 9) & 3, kc = i >> 11;
        int k = kc * 32 + ((lane >> 4) << 3) + j;
        int col = tile * 16 + (lane & 15);
        Bf[i] = (_Float16)W[k * 64 + col];
    }
    __syncthreads();
    const int lane = tid & 63, wid = tid >> 6;
    const int mrow = lane & 15, quad = lane >> 4;
    #pragma unroll
    for (int tt = 0; tt < 4; ++tt) {
        const int base = (blockIdx.x * 4 + tt) * 64 + wid * 16;
        if (base >= n) continue;
        const int anode = min(base + mrow, n - 1);
        floatx4 acc[4] = {{0, 0, 0, 0}, {0, 0, 0, 0}, {0, 0, 0, 0}, {0, 0, 0, 0}};
        #pragma unroll
        for (int kc = 0; kc < KC; ++kc) {
            half8 a = *(const half8*)&Xh[(size_t)anode * K + kc * 32 + quad * 8];
            #pragma unroll
            for (int t = 0; t < 4; ++t) {
                half8 b = *(const half8*)&Bf[((kc * 4 + t) * 64 + lane) * 8];
                acc[t] = __builtin_amdgcn_mfma_f32_16x16x32_f16(a, b, acc[t], 0, 0, 0);
            }
        }
        #pragma unroll
        for (int r = 0; r < 4; ++r) {
            int node = base + quad * 4 + r;
            if (node < n) {
                float di = dinv[node];
                #pragma unroll
                for (int t = 0; t < 4; ++t)
                    Y[(size_t)node * 64 + t * 16 + mrow] = (_Float16)(acc[t][r] * di);
            }
        }
    }
}

// ---------------- linear3: Y16[n][8] = fp16(pad8((Xh@W3)*dinv)) ----------------
__global__ __launch_bounds__(256) void linear3_kernel(const __half* __restrict__ Xh,
                                                      const float* __restrict__ W,
                                                      const float* __restrict__ dinv,
                                                      __half* __restrict__ Y, int n) {
    __shared__ float Wl[64 * 6];
    __shared__ float Xs[32][65];
    const int tid = threadIdx.x;
    for (int i = tid; i < 64 * 6; i += 256) Wl[i] = W[i];
    const int sub = tid >> 3;
    const int feat = tid & 7;
    for (int base = blockIdx.x * 32; base < n; base += gridDim.x * 32) {
        __syncthreads();
        for (int i = tid; i < 32 * 64; i += 256) {
            int r = i >> 6, c = i & 63;
            int node = base + r;
            Xs[r][c] = (node < n) ? __half2float(Xh[(size_t)node * 64 + c]) : 0.f;
        }
        __syncthreads();
        int node = base + sub;
        if (node < n) {
            float r = 0.f;
            if (feat < 6) {
                float acc = 0.f;
                #pragma unroll
                for (int k = 0; k < 64; ++k) acc = fmaf(Xs[sub][k], Wl[k * 6 + feat], acc);
                r = acc * dinv[node];
            }
            Y[(size_t)node * 8 + feat] = __float2half_rn(r);
        }
    }
}

// ---------------- aggregate 64 feats: wave/node, packed accum, unroll-4 ----------------
__global__ __launch_bounds__(256) void agg64_kernel(
    const _Float16* __restrict__ Hs, const float* __restrict__ dinv,
    const int* __restrict__ srcS, const int2* __restrict__ rows,
    const float* __restrict__ bias, _Float16* __restrict__ Out,
    int n, int do_relu) {
    const int wave = (blockIdx.x * blockDim.x + threadIdx.x) >> 6;
    const int lane = threadIdx.x & 63;
    if (wave >= n) return;
    const int slot = lane >> 3;  // edge slot 0..7
    const int f8 = lane & 7;     // feat slice [f8*8, f8*8+8)
    const int2 row = rows[wave];
    const int beg = row.x, end = row.y;
    // hoisted independent loads: in flight while the edge loop runs
    half8 self = *(const half8*)&Hs[(size_t)wave * 64 + f8 * 8];
    const float di = dinv[wave];
    float4 b0 = *(const float4*)&bias[f8 * 8];
    float4 b1 = *(const float4*)&bias[f8 * 8 + 4];
    half8 hA, hB;
    #pragma unroll
    for (int i = 0; i < 8; ++i) { hA[i] = (_Float16)0.f; hB[i] = (_Float16)0.f; }
    int j = beg;
    for (; j + 32 <= end; j += 32) {      // 32 edges: 4 gathers in flight
        int s0 = __builtin_nontemporal_load(srcS + j      + slot);
        int s1 = __builtin_nontemporal_load(srcS + j + 8  + slot);
        int s2 = __builtin_nontemporal_load(srcS + j + 16 + slot);
        int s3 = __builtin_nontemporal_load(srcS + j + 24 + slot);
        half8 v0 = *(const half8*)&Hs[(size_t)s0 * 64 + f8 * 8];
        half8 v1 = *(const half8*)&Hs[(size_t)s1 * 64 + f8 * 8];
        half8 v2 = *(const half8*)&Hs[(size_t)s2 * 64 + f8 * 8];
        half8 v3 = *(const half8*)&Hs[(size_t)s3 * 64 + f8 * 8];
        hA += v0; hB += v1; hA += v2; hB += v3;
    }
    for (; j + 16 <= end; j += 16) {      // 16 edges
        int s0 = __builtin_nontemporal_load(srcS + j + slot);
        int s1 = __builtin_nontemporal_load(srcS + j + 8 + slot);
        half8 v0 = *(const half8*)&Hs[(size_t)s0 * 64 + f8 * 8];
        half8 v1 = *(const half8*)&Hs[(size_t)s1 * 64 + f8 * 8];
        hA += v0; hB += v1;
    }
    for (; j < end; j += 8) {             // tail, 8 edges (exec-masked)
        int jj = j + slot;
        if (jj < end) {
            int s0 = __builtin_nontemporal_load(srcS + jj);
            half8 v = *(const half8*)&Hs[(size_t)s0 * 64 + f8 * 8];
            hA += v;
        }
    }
    half8 ht = hA + hB;
    #pragma unroll
    for (int mask = 8; mask <= 32; mask <<= 1) {  // packed fold over slots
        int4 ci = *(int4*)&ht, oi;
        oi.x = __shfl_xor(ci.x, mask);
        oi.y = __shfl_xor(ci.y, mask);
        oi.z = __shfl_xor(ci.z, mask);
        oi.w = __shfl_xor(ci.w, mask);
        ht += *(half8*)&oi;
    }
    float bb[8] = {b0.x, b0.y, b0.z, b0.w, b1.x, b1.y, b1.z, b1.w};
    half8 o;
    #pragma unroll
    for (int i = 0; i < 8; ++i) {
        float t = ((float)ht[i] + (float)self[i]) * di + bb[i];
        if (do_relu) t = fmaxf(t, 0.f);
        o[i] = (_Float16)t;
    }
    if (slot == 0) {
        intx4* op = (intx4*)&Out[(size_t)wave * 64 + f8 * 8];
        __builtin_nontemporal_store(*(intx4*)&o, op);
    }
}

// ---------------- aggregate 6 feats + bias + log_softmax: lane-per-edge ----------------
__global__ __launch_bounds__(256) void agg6_lsm_kernel(
    const _Float16* __restrict__ Hs6, const float* __restrict__ dinv,
    const int* __restrict__ srcS, const int2* __restrict__ rows,
    const float* __restrict__ bias, float* __restrict__ out, int n) {
    const int wave = (blockIdx.x * blockDim.x + threadIdx.x) >> 6;
    const int lane = threadIdx.x & 63;
    if (wave >= n) return;
    const int2 row = rows[wave];
    const int beg = row.x, end = row.y;
    half8 ht;
    #pragma unroll
    for (int i = 0; i < 8; ++i) ht[i] = (_Float16)0.f;
    for (int j = beg + lane; j < end; j += 64) {          // 1 iter typ. (deg~32)
        int s = __builtin_nontemporal_load(srcS + j);
        ht += *(const half8*)&Hs6[(size_t)s * 8];          // 16B row gather
    }
    #pragma unroll
    for (int mask = 1; mask <= 32; mask <<= 1) {          // packed fold, 64 lanes
        int4 ci = *(int4*)&ht, oi;
        oi.x = __shfl_xor(ci.x, mask);
        oi.y = __shfl_xor(ci.y, mask);
        oi.z = __shfl_xor(ci.z, mask);
        oi.w = __shfl_xor(ci.w, mask);
        ht += *(half8*)&oi;
    }
    // all lanes now hold the full edge-sum; redundant per-lane epilogue
    half8 self = *(const half8*)&Hs6[(size_t)wave * 8];
    const float di = dinv[wave];
    float a[6];
    #pragma unroll
    for (int q = 0; q < 6; ++q)
        a[q] = ((float)ht[q] + (float)self[q]) * di + bias[q];
    float mx = a[0];
    #pragma unroll
    for (int q = 1; q < 6; ++q) mx = fmaxf(mx, a[q]);
    float sum = 0.f;
    #pragma unroll
    for (int q = 0; q < 6; ++q) sum += expf(a[q] - mx);
    float lse = mx + logf(sum);
    if (lane == 0) {
        float* op = &out[(size_t)wave * 6];               // 24B-aligned -> 8B stores
        *(float2*)(op)     = make_float2(a[0] - lse, a[1] - lse);
        *(float2*)(op + 2) = make_float2(a[2] - lse, a[3] - lse);
        *(float2*)(op + 4) = make_float2(a[4] - lse, a[5] - lse);
    }
}

// ---------------------------------------------------------------------------
extern "C" void kernel_launch(void* const* d_in, const int* in_sizes, int n_in,
                              void* d_out, int out_size, void* d_ws, size_t ws_size,
                              hipStream_t stream) {
    const float* x  = (const float*)d_in[0];
    const int*   ei = (const int*)d_in[1];
    const float* W1 = (const float*)d_in[2];
    const float* b1 = (const float*)d_in[3];
    const float* W2 = (const float*)d_in[4];
    const float* b2 = (const float*)d_in[5];
    const float* W3 = (const float*)d_in[6];
    const float* b3 = (const float*)d_in[7];
    float* out = (float*)d_out;

    const int n = in_sizes[0] / 128;  // 100000
    const int E = in_sizes[1] / 2;    // 3200000
    const int* src = ei;
    const int* dst = ei + E;
    const int NB = (n + BKN - 1) / BKN;  // 782

    // ---- workspace carve ----
    char* ws = (char*)d_ws;
    auto carve = [&](size_t bytes) { char* p = ws; ws += WS_ALIGN(bytes); return p; };
    int*      cur  = (int*)     carve((size_t)NB * 4);
    float*    dinv = (float*)   carve((size_t)n * 4);
    int*      slab = (int*)     carve((size_t)NB * CAP * 4);   // 14.4 MB
    int*      srcS = (int*)     carve((size_t)NB * CAP * 4);   // 14.4 MB
    int2*     rows = (int2*)    carve((size_t)n * 8);
    _Float16* hsA  = (_Float16*)carve((size_t)n * 64 * 2 + 4096);   // 12.8 MB
    _Float16* hsB  = (_Float16*)carve((size_t)n * 64 * 2 + 4096);   // 12.8 MB
    _Float16* hsC  = (_Float16*)carve((size_t)n * 8 * 2);           // 1.6 MB
    (void)ws_size; (void)n_in; (void)out_size;

    // ---- build CSR ----
    (void)hipMemsetAsync(cur, 0, (size_t)NB * 4, stream);
    bin_kernel<<<(E + BIN_CHUNK - 1) / BIN_CHUNK, BIN_THR, 0, stream>>>(src, dst, cur, slab, E, NB);
    bucket_sort_kernel<<<NB, 512, 0, stream>>>(slab, cur, srcS, rows, dinv, n);

    const int aggGrid = (n + 3) / 4;       // wave per node, 4 waves/WG
    const int linGrid = (n + 255) / 256;   // 256 nodes per WG (4 tiles)

    // ---- layer 1 ----
    linear_mfma_f32_kernel<128><<<linGrid, 256, 0, stream>>>(x, W1, dinv, hsA, n);
    agg64_kernel<<<aggGrid, 256, 0, stream>>>(hsA, dinv, srcS, rows, b1, hsB, n, 1);

    // ---- layer 2 ----
    linear_mfma_f16_kernel<<<linGrid, 256, 0, stream>>>(hsB, W2, dinv, hsA, n);
    agg64_kernel<<<aggGrid, 256, 0, stream>>>(hsA, dinv, srcS, rows, b2, hsB, n, 1);

    // ---- layer 3 ----
    linear3_kernel<<<2048, 256, 0, stream>>>((const __half*)hsB, W3, dinv, (__half*)hsC, n);
    agg6_lsm_kernel<<<(n + 3) / 4, 256, 0, stream>>>(hsC, dinv, srcS, rows, b3, out, n);
}

// Round 5
// 355.996 us; speedup vs baseline: 1.6103x; 1.0403x over previous
//
#include <hip/hip_runtime.h>
#include <hip/hip_fp16.h>
#include <math.h>

// ---------------------------------------------------------------------------
// GCN 3-layer forward, round 15.
// out[i] = dinv[i] * ( sum_{e:dst=i} Hs[src] + Hs[i] ) + b,  Hs = (X@W)*dinv.
// Round-15 delta vs round-11 (agg kernels reverted to exact round-11 form):
//  - bin_kernel: in-LDS counting sort (histogram -> scan -> stage -> burst
//    write). Edges leave the WG sorted by bucket, so each bucket's run is a
//    contiguous global write (was: 3.2M random 4B writes, ~16x line RMW
//    amplification over a 14.4MB slab set > 4MB L2/XCD).
//  - BKN 128 -> 256 (NB=391, CAP=9216): doubles mean run length (10.5 edges
//    ~42B), halving residual write fragmentation; bucket_sort adjusted.
// ---------------------------------------------------------------------------

#define WS_ALIGN(x) (((x) + 255) & ~(size_t)255)
#define BKN 256                 // nodes per bin/sort bucket
#define CAP 9216                // slab capacity per bucket (mean 8184; +11 sigma)
#define EPT 8                   // edges per thread in bin kernel
#define BIN_THR 512
#define BIN_CHUNK (BIN_THR * EPT)  // 4096 edges per WG

typedef _Float16 half8 __attribute__((ext_vector_type(8)));
typedef float floatx4 __attribute__((ext_vector_type(4)));

// ---------------- binning: LDS counting sort + coalesced burst scatter ----------------
__global__ __launch_bounds__(BIN_THR) void bin_kernel(
    const int* __restrict__ src, const int* __restrict__ dst,
    int* __restrict__ cur, int* __restrict__ slab, int E, int NB) {
    __shared__ int cnt[512];    // per-bucket count (NB = 391)
    __shared__ int incl[512];   // inclusive scan of cnt
    __shared__ int gbase[512];  // reserved global base per bucket
    __shared__ int stag[BIN_CHUNK];  // 16KB staging, sorted by bucket
    const int tid = threadIdx.x;
    const int base = blockIdx.x * BIN_CHUNK + tid * EPT;  // contiguous per thread
    cnt[tid] = 0;
    __syncthreads();
    int b[EPT], w[EPT], lp[EPT];
    #pragma unroll
    for (int k = 0; k < EPT; ++k) {
        int e = base + k;
        if (e < E) {
            int s = src[e], d = dst[e];   // vectorized int4 loads
            b[k] = d >> 8;
            w[k] = (s << 8) | (d & 255);
        } else b[k] = -1;
    }
    #pragma unroll
    for (int k = 0; k < EPT; ++k)
        if (b[k] >= 0) lp[k] = atomicAdd(&cnt[b[k]], 1);
    __syncthreads();
    // Hillis-Steele inclusive scan over 512 slots (NB <= 512), 1 elem/thread
    incl[tid] = cnt[tid];
    __syncthreads();
    for (int off = 1; off < 512; off <<= 1) {
        int v = 0;
        if (tid >= off) v = incl[tid - off];
        __syncthreads();
        incl[tid] += v;
        __syncthreads();
    }
    // reserve contiguous global run per nonzero bucket
    if (tid < NB) {
        int c = cnt[tid];
        gbase[tid] = c ? atomicAdd(&cur[tid], c) : 0;
    }
    // stage sorted-by-bucket into LDS
    #pragma unroll
    for (int k = 0; k < EPT; ++k)
        if (b[k] >= 0) stag[incl[b[k]] - cnt[b[k]] + lp[k]] = w[k];
    __syncthreads();
    const int total = incl[NB - 1];
    // burst write: consecutive lanes -> consecutive slots of the same run
    for (int idx = tid; idx < total; idx += BIN_THR) {
        int wv = stag[idx];
        int lo = 0, hi = NB - 1;            // smallest bucket with incl>idx
        while (lo < hi) { int mid = (lo + hi) >> 1; if (incl[mid] > idx) hi = mid; else lo = mid + 1; }
        int excl = incl[lo] - cnt[lo];
        int p = gbase[lo] + (idx - excl);
        if (p < CAP) slab[(size_t)lo * CAP + p] = wv;
    }
}

// ---------------- per-bucket counting sort -> per-node CSR + dinv ----------------
__global__ __launch_bounds__(512) void bucket_sort_kernel(
    const int* __restrict__ slab, const int* __restrict__ cur,
    int* __restrict__ srcS, int2* __restrict__ rows,
    float* __restrict__ dinv, int n) {
    __shared__ int cnt[BKN], s[BKN], cursor[BKN];
    const int b = blockIdx.x, tid = threadIdx.x;
    const int m = min(cur[b], CAP);
    const int* sp = slab + (size_t)b * CAP;
    if (tid < BKN) cnt[tid] = 0;
    __syncthreads();
    for (int j = tid; j < m; j += 512) atomicAdd(&cnt[sp[j] & (BKN - 1)], 1);
    __syncthreads();
    if (tid < BKN) s[tid] = cnt[tid];
    __syncthreads();
    // Hillis-Steele inclusive scan over BKN entries
    for (int off = 1; off < BKN; off <<= 1) {
        int v = 0;
        if (tid < BKN && tid >= off) v = s[tid - off];
        __syncthreads();
        if (tid < BKN) s[tid] += v;
        __syncthreads();
    }
    if (tid < BKN) {
        int ofs = s[tid] - cnt[tid];  // exclusive
        cursor[tid] = ofs;
        int node = b * BKN + tid;
        if (node < n) {
            rows[node] = make_int2(b * CAP + ofs, b * CAP + ofs + cnt[tid]);
            dinv[node] = rsqrtf((float)(cnt[tid] + 1));  // +1 self loop
        }
    }
    __syncthreads();
    for (int j = tid; j < m; j += 512) {
        int w = sp[j];
        int p = atomicAdd(&cursor[w & (BKN - 1)], 1);
        srcS[(size_t)b * CAP + p] = w >> 8;  // writes land in a 36KB window
    }
}

// ---------------- MFMA linear (fp32 input): Y16 = fp16((Xf@W)*dinv) ----------------
// 4 node-tiles per WG: W staged once per 256 nodes.
// mfma_f32_16x16x32_f16: A[m=lane&15][k=(lane>>4)*8+j], C/D col=lane&15, row=quad*4+r.
template <int K>
__global__ __launch_bounds__(256) void linear_mfma_f32_kernel(
    const float* __restrict__ Xf, const float* __restrict__ W,
    const float* __restrict__ dinv, _Float16* __restrict__ Y, int n) {
    constexpr int KC = K / 32;
    __shared__ _Float16 Bf[KC * 4 * 64 * 8];  // B-fragment order; K=128 -> 16KB
    const int tid = threadIdx.x;
    for (int i = tid; i < KC * 4 * 64 * 8; i += 256) {
        int j = i & 7, lane = (i >> 3) & 63, tile = (i >> 9) & 3, kc = i >> 11;
        int k = kc * 32 + ((lane >> 4) << 3) + j;
        int col = tile * 16 + (lane & 15);
        Bf[i] = (_Float16)W[k * 64 + col];
    }
    __syncthreads();
    const int lane = tid & 63, wid = tid >> 6;
    const int mrow = lane & 15, quad = lane >> 4;
    #pragma unroll
    for (int tt = 0; tt < 4; ++tt) {
        const int base = (blockIdx.x * 4 + tt) * 64 + wid * 16;
        if (base >= n) continue;
        const int anode = min(base + mrow, n - 1);
        floatx4 acc[4] = {{0, 0, 0, 0}, {0, 0, 0, 0}, {0, 0, 0, 0}, {0, 0, 0, 0}};
        #pragma unroll
        for (int kc = 0; kc < KC; ++kc) {
            float4 xa = *(const float4*)&Xf[(size_t)anode * K + kc * 32 + quad * 8];
            float4 xb = *(const float4*)&Xf[(size_t)anode * K + kc * 32 + quad * 8 + 4];
            half8 a;
            a[0] = (_Float16)xa.x; a[1] = (_Float16)xa.y; a[2] = (_Float16)xa.z; a[3] = (_Float16)xa.w;
            a[4] = (_Float16)xb.x; a[5] = (_Float16)xb.y; a[6] = (_Float16)xb.z; a[7] = (_Float16)xb.w;
            #pragma unroll
            for (int t = 0; t < 4; ++t) {
                half8 b = *(const half8*)&Bf[((kc * 4 + t) * 64 + lane) * 8];
                acc[t] = __builtin_amdgcn_mfma_f32_16x16x32_f16(a, b, acc[t], 0, 0, 0);
            }
        }
        #pragma unroll
        for (int r = 0; r < 4; ++r) {
            int node = base + quad * 4 + r;
            if (node < n) {
                float di = dinv[node];
                #pragma unroll
                for (int t = 0; t < 4; ++t)
                    Y[(size_t)node * 64 + t * 16 + mrow] = (_Float16)(acc[t][r] * di);
            }
        }
    }
}

// ---------------- MFMA linear (fp16 input), K=64, 4 tiles per WG ----------------
__global__ __launch_bounds__(256) void linear_mfma_f16_kernel(
    const _Float16* __restrict__ Xh, const float* __restrict__ W,
    const float* __restrict__ dinv, _Float16* __restrict__ Y, int n) {
    constexpr int K = 64, KC = 2;
    __shared__ _Float16 Bf[KC * 4 * 64 * 8];  // 8KB
    const int tid = threadIdx.x;
    for (int i = tid; i < KC * 4 * 64 * 8; i += 256) {
        int j = i & 7, lane = (i >> 3) & 63, tile = (i >> 9) & 3, kc = i >> 11;
        int k = kc * 32 + ((lane >> 4) << 3) + j;
        int col = tile * 16 + (lane & 15);
        Bf[i] = (_Float16)W[k * 64 + col];
    }
    __syncthreads();
    const int lane = tid & 63, wid = tid >> 6;
    const int mrow = lane & 15, quad = lane >> 4;
    #pragma unroll
    for (int tt = 0; tt < 4; ++tt) {
        const int base = (blockIdx.x * 4 + tt) * 64 + wid * 16;
        if (base >= n) continue;
        const int anode = min(base + mrow, n - 1);
        floatx4 acc[4] = {{0, 0, 0, 0}, {0, 0, 0, 0}, {0, 0, 0, 0}, {0, 0, 0, 0}};
        #pragma unroll
        for (int kc = 0; kc < KC; ++kc) {
            half8 a = *(const half8*)&Xh[(size_t)anode * K + kc * 32 + quad * 8];
            #pragma unroll
            for (int t = 0; t < 4; ++t) {
                half8 b = *(const half8*)&Bf[((kc * 4 + t) * 64 + lane) * 8];
                acc[t] = __builtin_amdgcn_mfma_f32_16x16x32_f16(a, b, acc[t], 0, 0, 0);
            }
        }
        #pragma unroll
        for (int r = 0; r < 4; ++r) {
            int node = base + quad * 4 + r;
            if (node < n) {
                float di = dinv[node];
                #pragma unroll
                for (int t = 0; t < 4; ++t)
                    Y[(size_t)node * 64 + t * 16 + mrow] = (_Float16)(acc[t][r] * di);
            }
        }
    }
}

// ---------------- linear3: Y16[n][8] = fp16(pad8((Xh@W3)*dinv)) ----------------
__global__ __launch_bounds__(256) void linear3_kernel(const __half* __restrict__ Xh,
                                                      const float* __restrict__ W,
                                                      const float* __restrict__ dinv,
                                                      __half* __restrict__ Y, int n) {
    __shared__ float Wl[64 * 6];
    __shared__ float Xs[32][65];
    const int tid = threadIdx.x;
    for (int i = tid; i < 64 * 6; i += 256) Wl[i] = W[i];
    const int sub = tid >> 3;
    const int feat = tid & 7;
    for (int base = blockIdx.x * 32; base < n; base += gridDim.x * 32) {
        __syncthreads();
        for (int i = tid; i < 32 * 64; i += 256) {
            int r = i >> 6, c = i & 63;
            int node = base + r;
            Xs[r][c] = (node < n) ? __half2float(Xh[(size_t)node * 64 + c]) : 0.f;
        }
        __syncthreads();
        int node = base + sub;
        if (node < n) {
            float r = 0.f;
            if (feat < 6) {
                float acc = 0.f;
                #pragma unroll
                for (int k = 0; k < 64; ++k) acc = fmaf(Xs[sub][k], Wl[k * 6 + feat], acc);
                r = acc * dinv[node];
            }
            Y[(size_t)node * 8 + feat] = __float2half_rn(r);
        }
    }
}

// ---------------- aggregate 64 feats: wave/node, packed accum, unroll-4 ----------------
__global__ __launch_bounds__(256) void agg64_kernel(
    const _Float16* __restrict__ Hs, const float* __restrict__ dinv,
    const int* __restrict__ srcS, const int2* __restrict__ rows,
    const float* __restrict__ bias, _Float16* __restrict__ Out,
    int n, int do_relu) {
    const int wave = (blockIdx.x * blockDim.x + threadIdx.x) >> 6;
    const int lane = threadIdx.x & 63;
    if (wave >= n) return;
    const int slot = lane >> 3;  // edge slot 0..7
    const int f8 = lane & 7;     // feat slice [f8*8, f8*8+8)
    const int2 row = rows[wave];
    const int beg = row.x, end = row.y;
    half8 hA, hB;
    #pragma unroll
    for (int i = 0; i < 8; ++i) { hA[i] = (_Float16)0.f; hB[i] = (_Float16)0.f; }
    int j = beg;
    for (; j + 32 <= end; j += 32) {      // 32 edges: 4 gathers in flight
        int s0 = srcS[j      + slot];
        int s1 = srcS[j + 8  + slot];
        int s2 = srcS[j + 16 + slot];
        int s3 = srcS[j + 24 + slot];
        half8 v0 = *(const half8*)&Hs[(size_t)s0 * 64 + f8 * 8];
        half8 v1 = *(const half8*)&Hs[(size_t)s1 * 64 + f8 * 8];
        half8 v2 = *(const half8*)&Hs[(size_t)s2 * 64 + f8 * 8];
        half8 v3 = *(const half8*)&Hs[(size_t)s3 * 64 + f8 * 8];
        hA += v0; hB += v1; hA += v2; hB += v3;
    }
    for (; j + 16 <= end; j += 16) {      // 16 edges
        int s0 = srcS[j + slot];
        int s1 = srcS[j + 8 + slot];
        half8 v0 = *(const half8*)&Hs[(size_t)s0 * 64 + f8 * 8];
        half8 v1 = *(const half8*)&Hs[(size_t)s1 * 64 + f8 * 8];
        hA += v0; hB += v1;
    }
    for (; j < end; j += 8) {             // tail, 8 edges (exec-masked)
        int jj = j + slot;
        if (jj < end) {
            half8 v = *(const half8*)&Hs[(size_t)srcS[jj] * 64 + f8 * 8];
            hA += v;
        }
    }
    half8 ht = hA + hB;
    #pragma unroll
    for (int mask = 8; mask <= 32; mask <<= 1) {  // packed fold over slots
        int4 ci = *(int4*)&ht, oi;
        oi.x = __shfl_xor(ci.x, mask);
        oi.y = __shfl_xor(ci.y, mask);
        oi.z = __shfl_xor(ci.z, mask);
        oi.w = __shfl_xor(ci.w, mask);
        ht += *(half8*)&oi;
    }
    half8 self = *(const half8*)&Hs[(size_t)wave * 64 + f8 * 8];
    const float di = dinv[wave];
    float4 b0 = *(const float4*)&bias[f8 * 8];
    float4 b1 = *(const float4*)&bias[f8 * 8 + 4];
    float bb[8] = {b0.x, b0.y, b0.z, b0.w, b1.x, b1.y, b1.z, b1.w};
    half8 o;
    #pragma unroll
    for (int i = 0; i < 8; ++i) {
        float t = ((float)ht[i] + (float)self[i]) * di + bb[i];
        if (do_relu) t = fmaxf(t, 0.f);
        o[i] = (_Float16)t;
    }
    if (slot == 0) *(half8*)&Out[(size_t)wave * 64 + f8 * 8] = o;
}

// ---------------- aggregate 6 feats + bias + log_softmax: lane-per-edge ----------------
__global__ __launch_bounds__(256) void agg6_lsm_kernel(
    const _Float16* __restrict__ Hs6, const float* __restrict__ dinv,
    const int* __restrict__ srcS, const int2* __restrict__ rows,
    const float* __restrict__ bias, float* __restrict__ out, int n) {
    const int wave = (blockIdx.x * blockDim.x + threadIdx.x) >> 6;
    const int lane = threadIdx.x & 63;
    if (wave >= n) return;
    const int2 row = rows[wave];
    const int beg = row.x, end = row.y;
    half8 ht;
    #pragma unroll
    for (int i = 0; i < 8; ++i) ht[i] = (_Float16)0.f;
    for (int j = beg + lane; j < end; j += 64) {          // 1 iter typ. (deg~32)
        int s = srcS[j];
        ht += *(const half8*)&Hs6[(size_t)s * 8];          // 16B row gather
    }
    #pragma unroll
    for (int mask = 1; mask <= 32; mask <<= 1) {          // packed fold, 64 lanes
        int4 ci = *(int4*)&ht, oi;
        oi.x = __shfl_xor(ci.x, mask);
        oi.y = __shfl_xor(ci.y, mask);
        oi.z = __shfl_xor(ci.z, mask);
        oi.w = __shfl_xor(ci.w, mask);
        ht += *(half8*)&oi;
    }
    // all lanes now hold the full edge-sum; redundant per-lane epilogue
    half8 self = *(const half8*)&Hs6[(size_t)wave * 8];
    const float di = dinv[wave];
    float a[6];
    #pragma unroll
    for (int q = 0; q < 6; ++q)
        a[q] = ((float)ht[q] + (float)self[q]) * di + bias[q];
    float mx = a[0];
    #pragma unroll
    for (int q = 1; q < 6; ++q) mx = fmaxf(mx, a[q]);
    float sum = 0.f;
    #pragma unroll
    for (int q = 0; q < 6; ++q) sum += expf(a[q] - mx);
    float lse = mx + logf(sum);
    if (lane == 0) {
        float* op = &out[(size_t)wave * 6];               // 24B-aligned -> 8B stores
        *(float2*)(op)     = make_float2(a[0] - lse, a[1] - lse);
        *(float2*)(op + 2) = make_float2(a[2] - lse, a[3] - lse);
        *(float2*)(op + 4) = make_float2(a[4] - lse, a[5] - lse);
    }
}

// ---------------------------------------------------------------------------
extern "C" void kernel_launch(void* const* d_in, const int* in_sizes, int n_in,
                              void* d_out, int out_size, void* d_ws, size_t ws_size,
                              hipStream_t stream) {
    const float* x  = (const float*)d_in[0];
    const int*   ei = (const int*)d_in[1];
    const float* W1 = (const float*)d_in[2];
    const float* b1 = (const float*)d_in[3];
    const float* W2 = (const float*)d_in[4];
    const float* b2 = (const float*)d_in[5];
    const float* W3 = (const float*)d_in[6];
    const float* b3 = (const float*)d_in[7];
    float* out = (float*)d_out;

    const int n = in_sizes[0] / 128;  // 100000
    const int E = in_sizes[1] / 2;    // 3200000
    const int* src = ei;
    const int* dst = ei + E;
    const int NB = (n + BKN - 1) / BKN;  // 391

    // ---- workspace carve ----
    char* ws = (char*)d_ws;
    auto carve = [&](size_t bytes) { char* p = ws; ws += WS_ALIGN(bytes); return p; };
    int*      cur  = (int*)     carve((size_t)NB * 4);
    float*    dinv = (float*)   carve((size_t)n * 4);
    int*      slab = (int*)     carve((size_t)NB * CAP * 4);   // 14.4 MB
    int*      srcS = (int*)     carve((size_t)NB * CAP * 4);   // 14.4 MB
    int2*     rows = (int2*)    carve((size_t)n * 8);
    _Float16* hsA  = (_Float16*)carve((size_t)n * 64 * 2 + 4096);   // 12.8 MB
    _Float16* hsB  = (_Float16*)carve((size_t)n * 64 * 2 + 4096);   // 12.8 MB
    _Float16* hsC  = (_Float16*)carve((size_t)n * 8 * 2);           // 1.6 MB
    (void)ws_size; (void)n_in; (void)out_size;

    // ---- build CSR ----
    (void)hipMemsetAsync(cur, 0, (size_t)NB * 4, stream);
    bin_kernel<<<(E + BIN_CHUNK - 1) / BIN_CHUNK, BIN_THR, 0, stream>>>(src, dst, cur, slab, E, NB);
    bucket_sort_kernel<<<NB, 512, 0, stream>>>(slab, cur, srcS, rows, dinv, n);

    const int aggGrid = (n + 3) / 4;       // wave per node, 4 waves/WG
    const int linGrid = (n + 255) / 256;   // 256 nodes per WG (4 tiles)

    // ---- layer 1 ----
    linear_mfma_f32_kernel<128><<<linGrid, 256, 0, stream>>>(x, W1, dinv, hsA, n);
    agg64_kernel<<<aggGrid, 256, 0, stream>>>(hsA, dinv, srcS, rows, b1, hsB, n, 1);

    // ---- layer 2 ----
    linear_mfma_f16_kernel<<<linGrid, 256, 0, stream>>>(hsB, W2, dinv, hsA, n);
    agg64_kernel<<<aggGrid, 256, 0, stream>>>(hsA, dinv, srcS, rows, b2, hsB, n, 1);

    // ---- layer 3 ----
    linear3_kernel<<<2048, 256, 0, stream>>>((const __half*)hsB, W3, dinv, (__half*)hsC, n);
    agg6_lsm_kernel<<<(n + 3) / 4, 256, 0, stream>>>(hsC, dinv, srcS, rows, b3, out, n);
}